// Round 4
// baseline (377.214 us; speedup 1.0000x reference)
//
#include <hip/hip_runtime.h>
#include <math.h>

// Problem constants (from reference setup_inputs)
#define BATCH 32
#define NPTS  4096
#define DCH   254            // input channels; output row = DCH + 2 = 256
#define OUTC  256
#define PB    64             // partial-reduce chunks per batch
#define NBLK1 (BATCH * PB)   // 2048 reduce blocks
#define EPSV  1e-5f

#define BFLOATS (NPTS * DCH)     // 1,040,384 floats per batch
#define B4      (BFLOATS / 4)    // 260,096 float4 per batch (batch base 16B-aligned)
#define C4      (B4 / PB)        // 4,064 float4 per chunk (= 64 rows)

#define NORM_BLOCKS 4096         // 32 rows/block, 128 blocks per batch
#define ROWS_PER_BLK2 (BATCH * NPTS / NORM_BLOCKS)   // 32

// native clang vector type: required by __builtin_nontemporal_store
typedef float floatx4 __attribute__((ext_vector_type(4)));

// ---------------------------------------------------------------------------
// MEASUREMENT ROUND: kernels are byte-identical to round 3. kernel_launch
// replicates ipn_norm x4 (idempotent: identical stores) so that
// (dur_us - 256.8)/3 = t_norm, and if t_norm > ~80us the norm dispatches
// surface in the top-5 rocprof table with full counters.
// ---------------------------------------------------------------------------

// ---------------------------------------------------------------------------
// Kernel 1: per-batch partial reduction, contiguous chunks.
// ---------------------------------------------------------------------------
__global__ __launch_bounds__(256) void ipn_reduce(const float* __restrict__ x,
                                                  float2* __restrict__ partials) {
    const int blk = blockIdx.x;
    const int b   = blk / PB;
    const int j   = blk % PB;
    const float4* xb = (const float4*)(x + (size_t)b * BFLOATS);

    float s = 0.f, ss = 0.f;
    const int i0 = j * C4;
    for (int i = i0 + threadIdx.x; i < i0 + C4; i += 256) {   // C4=4064: 15-16 iters
        float4 v = xb[i];
        s  += (v.x + v.y) + (v.z + v.w);
        ss += (v.x * v.x + v.y * v.y) + (v.z * v.z + v.w * v.w);
    }
    #pragma unroll
    for (int off = 32; off > 0; off >>= 1) {
        s  += __shfl_down(s, off);
        ss += __shfl_down(ss, off);
    }
    __shared__ float ls[4], lss[4];
    const int wv = threadIdx.x >> 6;
    if ((threadIdx.x & 63) == 0) { ls[wv] = s; lss[wv] = ss; }
    __syncthreads();
    if (threadIdx.x == 0) {
        partials[blk] = make_float2((ls[0]  + ls[1])  + (ls[2]  + ls[3]),
                                    (lss[0] + lss[1]) + (lss[2] + lss[3]));
    }
}

// ---------------------------------------------------------------------------
// Kernel 2: finalize (folded in) + normalize + concat(mean,std) + scale/bias.
// Identical to round 3.
// ---------------------------------------------------------------------------
__global__ __launch_bounds__(256) void ipn_norm(const float* __restrict__ x,
                                                const float* __restrict__ w,
                                                const float* __restrict__ bias,
                                                const float2* __restrict__ partials,
                                                float* __restrict__ out) {
    const int lane = threadIdx.x & 63;
    const int wv   = threadIdx.x >> 6;
    const int b    = blockIdx.x >> 7;          // 128 blocks per batch

    // ---- fold this batch's 64 partials (each wave redundantly, in-register) ----
    float2 p = partials[b * PB + lane];
    float S = p.x, SS = p.y;
    #pragma unroll
    for (int off = 32; off > 0; off >>= 1) {   // butterfly: every lane gets totals
        S  += __shfl_xor(S, off);
        SS += __shfl_xor(SS, off);
    }
    const float invM = 1.0f / (float)BFLOATS;
    const float mean = S * invM;
    const float var  = fmaxf(SS * invM - mean * mean, 0.f);   // biased variance
    const float stdv = sqrtf(var);
    const float inv  = 1.0f / (stdv + EPSV);

    // ---- per-lane fused scale/offset ----
    const int c0 = lane * 4;
    const float4 w4 = ((const float4*)w)[lane];
    const float4 b4 = ((const float4*)bias)[lane];
    float4 s4, o4;
    s4.x = inv * w4.x;  o4.x = b4.x - mean * s4.x;
    s4.y = inv * w4.y;  o4.y = b4.y - mean * s4.y;
    s4.z = inv * w4.z;  o4.z = b4.z - mean * s4.z;
    s4.w = inv * w4.w;  o4.w = b4.w - mean * s4.w;
    // lane 63 splice constants (cols 254=mean, 255=std), batch-invariant
    const float oz63 = mean * w4.z + b4.z;
    const float ow63 = stdv * w4.w + b4.w;

    const int row0 = blockIdx.x * ROWS_PER_BLK2;

    for (int r = wv; r < ROWS_PER_BLK2; r += 4) {
        const int row = row0 + r;
        const float* xr = x + (size_t)row * DCH + c0;
        const float2 lo = *(const float2*)xr;            // cols c0, c0+1
        floatx4 o;
        o.x = lo.x * s4.x + o4.x;
        o.y = lo.y * s4.y + o4.y;
        if (c0 < 252) {
            const float2 hi = *(const float2*)(xr + 2);  // cols c0+2, c0+3
            o.z = hi.x * s4.z + o4.z;
            o.w = hi.y * s4.w + o4.w;
        } else {                                          // lane 63
            o.z = oz63;
            o.w = ow63;
        }
        __builtin_nontemporal_store(o, (floatx4*)(out + (size_t)row * OUTC) + lane);
    }
}

// ---------------------------------------------------------------------------
extern "C" void kernel_launch(void* const* d_in, const int* in_sizes, int n_in,
                              void* d_out, int out_size, void* d_ws, size_t ws_size,
                              hipStream_t stream) {
    const float* x   = (const float*)d_in[0];   // [32, 4096, 254] fp32
    const float* wgt = (const float*)d_in[1];   // [256] fp32
    const float* bia = (const float*)d_in[2];   // [256] fp32
    float* out       = (float*)d_out;           // [32, 4096, 256] fp32

    float2* partials = (float2*)d_ws;           // 2048 * 8 B = 16 KB

    ipn_reduce<<<NBLK1, 256, 0, stream>>>(x, partials);
    // x4 replication: idempotent; (dur_us - round3)/3 = t_norm
    ipn_norm<<<NORM_BLOCKS, 256, 0, stream>>>(x, wgt, bia, partials, out);
    ipn_norm<<<NORM_BLOCKS, 256, 0, stream>>>(x, wgt, bia, partials, out);
    ipn_norm<<<NORM_BLOCKS, 256, 0, stream>>>(x, wgt, bia, partials, out);
    ipn_norm<<<NORM_BLOCKS, 256, 0, stream>>>(x, wgt, bia, partials, out);
}

// Round 5
// 255.352 us; speedup vs baseline: 1.4772x; 1.4772x over previous
//
#include <hip/hip_runtime.h>
#include <math.h>

// Problem constants (from reference setup_inputs)
#define BATCH 32
#define NPTS  4096
#define DCH   254            // input channels; output row = DCH + 2 = 256
#define OUTC  256
#define PB    64             // partial-reduce chunks per batch
#define NBLK1 (BATCH * PB)   // 2048 reduce blocks
#define EPSV  1e-5f

#define BFLOATS (NPTS * DCH)     // 1,040,384 floats per batch
#define B4      (BFLOATS / 4)    // 260,096 float4 per batch (batch base 16B-aligned)
#define C4      (B4 / PB)        // 4,064 float4 per chunk (= 64 rows)

#define NORM_BLOCKS 4096         // 32 rows/block, 128 blocks per batch
#define ROWS_PER_BLK2 (BATCH * NPTS / NORM_BLOCKS)   // 32

// ---------------------------------------------------------------------------
// Kernel 1: per-batch partial reduction, contiguous chunks (ascending sweep).
// Grid = 2048 blocks x 256 threads -> all blocks co-resident, HBM-BW-bound.
// Every partials slot is written unconditionally (0xAA-poisoned ws needs no init).
// ---------------------------------------------------------------------------
__global__ __launch_bounds__(256) void ipn_reduce(const float* __restrict__ x,
                                                  float2* __restrict__ partials) {
    const int blk = blockIdx.x;
    const int b   = blk / PB;
    const int j   = blk % PB;
    const float4* xb = (const float4*)(x + (size_t)b * BFLOATS);

    float s = 0.f, ss = 0.f;
    const int i0 = j * C4;
    for (int i = i0 + threadIdx.x; i < i0 + C4; i += 256) {   // C4=4064: 15-16 iters
        float4 v = xb[i];
        s  += (v.x + v.y) + (v.z + v.w);
        ss += (v.x * v.x + v.y * v.y) + (v.z * v.z + v.w * v.w);
    }
    #pragma unroll
    for (int off = 32; off > 0; off >>= 1) {
        s  += __shfl_down(s, off);
        ss += __shfl_down(ss, off);
    }
    __shared__ float ls[4], lss[4];
    const int wv = threadIdx.x >> 6;
    if ((threadIdx.x & 63) == 0) { ls[wv] = s; lss[wv] = ss; }
    __syncthreads();
    if (threadIdx.x == 0) {
        partials[blk] = make_float2((ls[0]  + ls[1])  + (ls[2]  + ls[3]),
                                    (lss[0] + lss[1]) + (lss[2] + lss[3]));
    }
}

// ---------------------------------------------------------------------------
// Kernel 2: finalize (folded in) + normalize + concat(mean,std) + scale/bias.
// Changes vs round 3 (t_norm measured 40us ~= full double-HBM traffic):
//  (a) REVERSED block->row mapping: norm walks x in descending address order.
//      out's 134 MB of L3 write-allocations evict LRU lines = lowest/oldest x
//      addresses; with an ascending walk that is exactly the data just ahead
//      of the read pointer (cascading ~100% miss). Descending, evictions hit
//      what we need LAST -> only the ~11 MB capacity overflow (133+134-256)
//      should miss to HBM.
//  (b) NT stores dropped (plain float4): Infinity Cache is memory-side, nt
//      can't protect x there anyway, and nt may defeat L2 write-combining
//      (fill kernel writes at 6.7 TB/s; norm looked like ~3.3 effective).
// ---------------------------------------------------------------------------
__global__ __launch_bounds__(256) void ipn_norm(const float* __restrict__ x,
                                                const float* __restrict__ w,
                                                const float* __restrict__ bias,
                                                const float2* __restrict__ partials,
                                                float* __restrict__ out) {
    const int lane = threadIdx.x & 63;
    const int wv   = threadIdx.x >> 6;
    const int rblk = (NORM_BLOCKS - 1) - blockIdx.x;   // reversed mapping
    const int b    = rblk >> 7;                        // 128 blocks per batch

    // ---- fold this batch's 64 partials (each wave redundantly, in-register) ----
    float2 p = partials[b * PB + lane];
    float S = p.x, SS = p.y;
    #pragma unroll
    for (int off = 32; off > 0; off >>= 1) {   // butterfly: every lane gets totals
        S  += __shfl_xor(S, off);
        SS += __shfl_xor(SS, off);
    }
    const float invM = 1.0f / (float)BFLOATS;
    const float mean = S * invM;
    const float var  = fmaxf(SS * invM - mean * mean, 0.f);   // biased variance
    const float stdv = sqrtf(var);
    const float inv  = 1.0f / (stdv + EPSV);

    // ---- per-lane fused scale/offset: out = v*(inv*w) + (b - mean*inv*w) ----
    const int c0 = lane * 4;
    const float4 w4 = ((const float4*)w)[lane];
    const float4 b4 = ((const float4*)bias)[lane];
    float4 s4, o4;
    s4.x = inv * w4.x;  o4.x = b4.x - mean * s4.x;
    s4.y = inv * w4.y;  o4.y = b4.y - mean * s4.y;
    s4.z = inv * w4.z;  o4.z = b4.z - mean * s4.z;
    s4.w = inv * w4.w;  o4.w = b4.w - mean * s4.w;
    // lane 63 splice constants (cols 254=mean, 255=std), batch-invariant
    const float oz63 = mean * w4.z + b4.z;
    const float ow63 = stdv * w4.w + b4.w;

    const int row0 = rblk * ROWS_PER_BLK2;

    for (int r = wv; r < ROWS_PER_BLK2; r += 4) {
        const int row = row0 + r;
        const float* xr = x + (size_t)row * DCH + c0;
        const float2 lo = *(const float2*)xr;            // cols c0, c0+1
        float4 o;
        o.x = lo.x * s4.x + o4.x;
        o.y = lo.y * s4.y + o4.y;
        if (c0 < 252) {
            const float2 hi = *(const float2*)(xr + 2);  // cols c0+2, c0+3
            o.z = hi.x * s4.z + o4.z;
            o.w = hi.y * s4.w + o4.w;
        } else {                                          // lane 63
            o.z = oz63;
            o.w = ow63;
        }
        ((float4*)(out + (size_t)row * OUTC))[lane] = o;
    }
}

// ---------------------------------------------------------------------------
extern "C" void kernel_launch(void* const* d_in, const int* in_sizes, int n_in,
                              void* d_out, int out_size, void* d_ws, size_t ws_size,
                              hipStream_t stream) {
    const float* x   = (const float*)d_in[0];   // [32, 4096, 254] fp32
    const float* wgt = (const float*)d_in[1];   // [256] fp32
    const float* bia = (const float*)d_in[2];   // [256] fp32
    float* out       = (float*)d_out;           // [32, 4096, 256] fp32

    float2* partials = (float2*)d_ws;           // 2048 * 8 B = 16 KB

    ipn_reduce<<<NBLK1, 256, 0, stream>>>(x, partials);
    ipn_norm<<<NORM_BLOCKS, 256, 0, stream>>>(x, wgt, bia, partials, out);
}